// Round 1
// baseline (849.813 us; speedup 1.0000x reference)
//
#include <hip/hip_runtime.h>

// Problem constants (from reference setup_inputs)
constexpr int N_NODES = 50000;
constexpr int E_EDGES = 800000;
constexpr int E_PAIR  = 200000;   // pos edges; neg edges same count
constexpr int C_IN    = 256;
constexpr int C_HID   = 128;
constexpr int C_OUT   = 64;

// ---------------------------------------------------------------------------
// Degree: deg[i] starts at 0 (memset); add 1 per incoming edge; self-loop
// folded into dinv kernel as +1.
// ---------------------------------------------------------------------------
__global__ void deg_kernel(const int* __restrict__ dst, float* __restrict__ deg) {
    int i = blockIdx.x * blockDim.x + threadIdx.x;
    if (i < E_EDGES) atomicAdd(&deg[dst[i]], 1.0f);
}

__global__ void dinv_kernel(float* __restrict__ deg) {
    int i = blockIdx.x * blockDim.x + threadIdx.x;
    if (i < N_NODES) deg[i] = rsqrtf(deg[i] + 1.0f);   // deg >= 1 always
}

// ---------------------------------------------------------------------------
// GEMM1: out[m,n] = dinv[m] * sum_k x[m,k]*W1[k,n]   (M=50000,K=256,N=128)
// 8 rows per 256-thread block; x tile staged in LDS; W streamed from cache.
// ---------------------------------------------------------------------------
__global__ __launch_bounds__(256) void gemm1_kernel(
        const float* __restrict__ x, const float* __restrict__ W,
        const float* __restrict__ dinv, float* __restrict__ out) {
    __shared__ float xs[8 * 256];
    const int t  = threadIdx.x;
    const int m0 = blockIdx.x * 8;          // 50000/8 = 6250 exact
#pragma unroll
    for (int i = 0; i < 8; ++i) {
        int idx = t + i * 256;              // 0..2047
        xs[idx] = x[(m0 + (idx >> 8)) * C_IN + (idx & 255)];
    }
    __syncthreads();
    const int n  = t & 127;
    const int rg = t >> 7;                  // 0..1 -> rows rg*4 .. rg*4+3
    const float* xr = &xs[rg * 4 * 256];
    float a0 = 0.f, a1 = 0.f, a2 = 0.f, a3 = 0.f;
#pragma unroll 4
    for (int k = 0; k < 256; ++k) {
        float wv = W[k * C_HID + n];        // coalesced across lanes
        a0 += xr[k]        * wv;            // LDS broadcast reads
        a1 += xr[256 + k]  * wv;
        a2 += xr[512 + k]  * wv;
        a3 += xr[768 + k]  * wv;
    }
    const int m = m0 + rg * 4;
    out[(m+0)*C_HID + n] = a0 * dinv[m+0];
    out[(m+1)*C_HID + n] = a1 * dinv[m+1];
    out[(m+2)*C_HID + n] = a2 * dinv[m+2];
    out[(m+3)*C_HID + n] = a3 * dinv[m+3];
}

// ---------------------------------------------------------------------------
// GEMM2: out[m,n] = dinv[m] * sum_k h[m,k]*W2[k,n]   (M=50000,K=128,N=64)
// 16 rows per 256-thread block.
// ---------------------------------------------------------------------------
__global__ __launch_bounds__(256) void gemm2_kernel(
        const float* __restrict__ h, const float* __restrict__ W,
        const float* __restrict__ dinv, float* __restrict__ out) {
    __shared__ float hs[16 * 128];
    const int t  = threadIdx.x;
    const int m0 = blockIdx.x * 16;         // 50000/16 = 3125 exact
#pragma unroll
    for (int i = 0; i < 8; ++i) {
        int idx = t + i * 256;              // 0..2047
        hs[idx] = h[(m0 + (idx >> 7)) * C_HID + (idx & 127)];
    }
    __syncthreads();
    const int n  = t & 63;
    const int rg = t >> 6;                  // 0..3 -> rows rg*4 .. rg*4+3
    const float* hr = &hs[rg * 4 * 128];
    float a0 = 0.f, a1 = 0.f, a2 = 0.f, a3 = 0.f;
#pragma unroll 4
    for (int k = 0; k < 128; ++k) {
        float wv = W[k * C_OUT + n];
        a0 += hr[k]        * wv;
        a1 += hr[128 + k]  * wv;
        a2 += hr[256 + k]  * wv;
        a3 += hr[384 + k]  * wv;
    }
    const int m = m0 + rg * 4;
    out[(m+0)*C_OUT + n] = a0 * dinv[m+0];
    out[(m+1)*C_OUT + n] = a1 * dinv[m+1];
    out[(m+2)*C_OUT + n] = a2 * dinv[m+2];
    out[(m+3)*C_OUT + n] = a3 * dinv[m+3];
}

// ---------------------------------------------------------------------------
// Scatter-add: agg[dst[e], f] += hsrc_scaled[src[e], f]
// One thread per (edge, feature). F is a compile-time param (128 or 64).
// ---------------------------------------------------------------------------
template<int F>
__global__ void scatter_kernel(const int* __restrict__ src, const int* __restrict__ dst,
                               const float* __restrict__ hs, float* __restrict__ agg) {
    int gid = blockIdx.x * blockDim.x + threadIdx.x;
    int e = gid / F;
    if (e >= E_EDGES) return;
    int f = gid % F;
    int s = src[e], d = dst[e];
    atomicAdd(&agg[d * F + f], hs[s * F + f]);
}

// ---------------------------------------------------------------------------
// finish: out = act( (agg + self_msg) * dinv[node] + bias )
// agg updated in place. RELU = layer-1 epilogue; layer 2 has none.
// ---------------------------------------------------------------------------
template<int F, bool RELU>
__global__ void finish_kernel(const float* __restrict__ hs, const float* __restrict__ dinv,
                              const float* __restrict__ bias, float* __restrict__ agg) {
    int gid = blockIdx.x * blockDim.x + threadIdx.x;
    if (gid >= N_NODES * F) return;
    int i = gid / F, f = gid % F;
    float v = (agg[gid] + hs[gid]) * dinv[i] + bias[f];
    agg[gid] = RELU ? fmaxf(v, 0.f) : v;
}

// ---------------------------------------------------------------------------
// logits[e] = dot(z[s], z[d]) over 64 features; one wave (64 lanes) per edge.
// ---------------------------------------------------------------------------
__global__ __launch_bounds__(256) void logits_kernel(
        const int* __restrict__ pos, const int* __restrict__ neg,
        const float* __restrict__ z, float* __restrict__ out) {
    const int t    = threadIdx.x;
    const int lane = t & 63;
    const int e    = blockIdx.x * 4 + (t >> 6);
    if (e >= 2 * E_PAIR) return;
    int s, d;
    if (e < E_PAIR) { s = pos[e];          d = pos[E_PAIR + e]; }
    else            { s = neg[e - E_PAIR]; d = neg[e];          } // neg[E_PAIR+(e-E_PAIR)]
    float v = z[s * C_OUT + lane] * z[d * C_OUT + lane];
#pragma unroll
    for (int off = 32; off > 0; off >>= 1) v += __shfl_down(v, off, 64);
    if (lane == 0) out[e] = v;
}

// ---------------------------------------------------------------------------
extern "C" void kernel_launch(void* const* d_in, const int* in_sizes, int n_in,
                              void* d_out, int out_size, void* d_ws, size_t ws_size,
                              hipStream_t stream) {
    const float* x   = (const float*)d_in[0];
    const int*   ei  = (const int*)d_in[1];   // [2, E] : row0=src, row1=dst
    const int*   pos = (const int*)d_in[2];   // [2, E_PAIR]
    const int*   neg = (const int*)d_in[3];   // [2, E_PAIR]
    const float* W1  = (const float*)d_in[4];
    const float* b1  = (const float*)d_in[5];
    const float* W2  = (const float*)d_in[6];
    const float* b2  = (const float*)d_in[7];
    float* out = (float*)d_out;

    const int* src = ei;
    const int* dst = ei + E_EDGES;

    // Workspace layout (bytes):
    //   [0)              dinv: 50000 f32                     (200704 aligned)
    //   [200704)         bufA: 50000*128 f32 = h0' then (z0' | z)
    //   [25800704)       bufB: 50000*128 f32 = agg1 -> h
    char* ws = (char*)d_ws;
    float* dinv = (float*)ws;
    float* bufA = (float*)(ws + 200704);
    float* bufB = (float*)(ws + 200704 + 25600000);
    float* z0s  = bufA;                       // 50000*64
    float* zbuf = bufA + N_NODES * C_OUT;     // 50000*64

    // 1. degree -> dinv
    hipMemsetAsync(dinv, 0, N_NODES * sizeof(float), stream);
    deg_kernel<<<(E_EDGES + 255) / 256, 256, 0, stream>>>(dst, dinv);
    dinv_kernel<<<(N_NODES + 255) / 256, 256, 0, stream>>>(dinv);

    // 2. h0' = (x@W1) * dinv[row]  -> bufA
    gemm1_kernel<<<N_NODES / 8, 256, 0, stream>>>(x, W1, dinv, bufA);

    // 3. layer-1 aggregation -> bufB, then h = relu((agg + h0')*dinv + b1)
    hipMemsetAsync(bufB, 0, (size_t)N_NODES * C_HID * sizeof(float), stream);
    {
        int total = E_EDGES * C_HID;
        scatter_kernel<C_HID><<<(total + 255) / 256, 256, 0, stream>>>(src, dst, bufA, bufB);
        int nt = N_NODES * C_HID;
        finish_kernel<C_HID, true><<<(nt + 255) / 256, 256, 0, stream>>>(bufA, dinv, b1, bufB);
    }

    // 4. z0' = (h@W2) * dinv[row] -> z0s (bufA lo half); agg2 -> zbuf (bufA hi half)
    gemm2_kernel<<<N_NODES / 16, 256, 0, stream>>>(bufB, W2, dinv, z0s);
    hipMemsetAsync(zbuf, 0, (size_t)N_NODES * C_OUT * sizeof(float), stream);
    {
        int total = E_EDGES * C_OUT;
        scatter_kernel<C_OUT><<<(total + 255) / 256, 256, 0, stream>>>(src, dst, z0s, zbuf);
        int nt = N_NODES * C_OUT;
        finish_kernel<C_OUT, false><<<(nt + 255) / 256, 256, 0, stream>>>(z0s, dinv, b2, zbuf);
    }

    // 5. logits over 400000 query edges
    logits_kernel<<<(2 * E_PAIR + 3) / 4, 256, 0, stream>>>(pos, neg, zbuf, out);
}

// Round 2
// 465.364 us; speedup vs baseline: 1.8261x; 1.8261x over previous
//
#include <hip/hip_runtime.h>

// Problem constants (from reference setup_inputs)
constexpr int N_NODES = 50000;
constexpr int E_EDGES = 800000;
constexpr int E_PAIR  = 200000;   // pos edges; neg edges same count
constexpr int C_IN    = 256;
constexpr int C_HID   = 128;
constexpr int C_OUT   = 64;

// ---------------------------------------------------------------------------
// In-degree counts (int). degc memset to 0 by host-side memsetAsync.
// ---------------------------------------------------------------------------
__global__ void count_kernel(const int* __restrict__ dst, int* __restrict__ degc) {
    int i = blockIdx.x * blockDim.x + threadIdx.x;
    if (i < E_EDGES) atomicAdd(&degc[dst[i]], 1);
}

// ---------------------------------------------------------------------------
// Segment allocation: per-block scan of 1024 degrees + one global atomicAdd
// for the block base. Segments are disjoint (monotonicity not needed for
// CSR gather). Also writes cursor (= row_ptr copy) and dinv = rsqrt(deg+1)
// (the +1 is the self-loop).
// ---------------------------------------------------------------------------
__global__ __launch_bounds__(256) void alloc_kernel(
        const int* __restrict__ degc, int* __restrict__ counter,
        int* __restrict__ row_ptr, int* __restrict__ cursor,
        float* __restrict__ dinv) {
    __shared__ int sums[256];
    __shared__ int base;
    const int t  = threadIdx.x;
    const int i0 = blockIdx.x * 1024 + t * 4;
    int v[4]; int s = 0;
#pragma unroll
    for (int j = 0; j < 4; ++j) {
        int idx = i0 + j;
        v[j] = (idx < N_NODES) ? degc[idx] : 0;
        s += v[j];
    }
    sums[t] = s;
    __syncthreads();
    for (int off = 1; off < 256; off <<= 1) {      // Hillis-Steele inclusive
        int x = (t >= off) ? sums[t - off] : 0;
        __syncthreads();
        if (t >= off) sums[t] += x;
        __syncthreads();
    }
    if (t == 255) base = atomicAdd(counter, sums[255]);
    __syncthreads();
    int excl = base + sums[t] - s;                 // exclusive offset, this thread
#pragma unroll
    for (int j = 0; j < 4; ++j) {
        int idx = i0 + j;
        if (idx < N_NODES) {
            row_ptr[idx] = excl;
            cursor[idx]  = excl;
            dinv[idx]    = rsqrtf((float)v[j] + 1.0f);
            excl += v[j];
        }
    }
}

// ---------------------------------------------------------------------------
// Fill CSR column (source ids), slot via per-node cursor atomic.
// ---------------------------------------------------------------------------
__global__ void fill_kernel(const int* __restrict__ src, const int* __restrict__ dst,
                            int* __restrict__ cursor, int* __restrict__ col) {
    int e = blockIdx.x * blockDim.x + threadIdx.x;
    if (e < E_EDGES) {
        int p = atomicAdd(&cursor[dst[e]], 1);
        col[p] = src[e];
    }
}

// ---------------------------------------------------------------------------
// GEMM1: out[m,n] = dinv[m] * sum_k x[m,k]*W1[k,n]   (M=50000,K=256,N=128)
// ---------------------------------------------------------------------------
__global__ __launch_bounds__(256) void gemm1_kernel(
        const float* __restrict__ x, const float* __restrict__ W,
        const float* __restrict__ dinv, float* __restrict__ out) {
    __shared__ float xs[8 * 256];
    const int t  = threadIdx.x;
    const int m0 = blockIdx.x * 8;          // 50000/8 = 6250 exact
#pragma unroll
    for (int i = 0; i < 8; ++i) {
        int idx = t + i * 256;              // 0..2047
        xs[idx] = x[(m0 + (idx >> 8)) * C_IN + (idx & 255)];
    }
    __syncthreads();
    const int n  = t & 127;
    const int rg = t >> 7;                  // 0..1 -> rows rg*4 .. rg*4+3
    const float* xr = &xs[rg * 4 * 256];
    float a0 = 0.f, a1 = 0.f, a2 = 0.f, a3 = 0.f;
#pragma unroll 4
    for (int k = 0; k < 256; ++k) {
        float wv = W[k * C_HID + n];        // coalesced across lanes
        a0 += xr[k]        * wv;            // LDS broadcast reads
        a1 += xr[256 + k]  * wv;
        a2 += xr[512 + k]  * wv;
        a3 += xr[768 + k]  * wv;
    }
    const int m = m0 + rg * 4;
    out[(m+0)*C_HID + n] = a0 * dinv[m+0];
    out[(m+1)*C_HID + n] = a1 * dinv[m+1];
    out[(m+2)*C_HID + n] = a2 * dinv[m+2];
    out[(m+3)*C_HID + n] = a3 * dinv[m+3];
}

// ---------------------------------------------------------------------------
// GEMM2: out[m,n] = dinv[m] * sum_k h[m,k]*W2[k,n]   (M=50000,K=128,N=64)
// ---------------------------------------------------------------------------
__global__ __launch_bounds__(256) void gemm2_kernel(
        const float* __restrict__ h, const float* __restrict__ W,
        const float* __restrict__ dinv, float* __restrict__ out) {
    __shared__ float hs[16 * 128];
    const int t  = threadIdx.x;
    const int m0 = blockIdx.x * 16;         // 50000/16 = 3125 exact
#pragma unroll
    for (int i = 0; i < 8; ++i) {
        int idx = t + i * 256;              // 0..2047
        hs[idx] = h[(m0 + (idx >> 7)) * C_HID + (idx & 127)];
    }
    __syncthreads();
    const int n  = t & 63;
    const int rg = t >> 6;                  // 0..3 -> rows rg*4 .. rg*4+3
    const float* hr = &hs[rg * 4 * 128];
    float a0 = 0.f, a1 = 0.f, a2 = 0.f, a3 = 0.f;
#pragma unroll 4
    for (int k = 0; k < 128; ++k) {
        float wv = W[k * C_OUT + n];
        a0 += hr[k]        * wv;
        a1 += hr[128 + k]  * wv;
        a2 += hr[256 + k]  * wv;
        a3 += hr[384 + k]  * wv;
    }
    const int m = m0 + rg * 4;
    out[(m+0)*C_OUT + n] = a0 * dinv[m+0];
    out[(m+1)*C_OUT + n] = a1 * dinv[m+1];
    out[(m+2)*C_OUT + n] = a2 * dinv[m+2];
    out[(m+3)*C_OUT + n] = a3 * dinv[m+3];
}

// ---------------------------------------------------------------------------
// CSR gather + epilogue. One wave (64 lanes) per node, 4 nodes per block.
// acc starts with the self-message hs[node]; neighbor ids broadcast via shfl.
// out = act((self + sum_nbr hs[s]) * dinv[node] + bias)
// hs rows are pre-scaled by dinv[src] in the GEMM epilogue, so this yields
// the full dinv[s]*dinv[d] edge normalization (self-loop included).
// ---------------------------------------------------------------------------
template<int F, bool RELU>
__global__ __launch_bounds__(256) void gather_kernel(
        const int* __restrict__ row_ptr, const int* __restrict__ degc,
        const int* __restrict__ col, const float* __restrict__ hs,
        const float* __restrict__ dinv, const float* __restrict__ bias,
        float* __restrict__ out) {
    const int lane = threadIdx.x & 63;
    const int node = blockIdx.x * 4 + (threadIdx.x >> 6);
    if (node >= N_NODES) return;
    const int rp = row_ptr[node];
    const int dg = degc[node];
    const float dn = dinv[node];

    if constexpr (F == 128) {
        const float2* hs2 = (const float2*)hs;
        float2 acc = hs2[(size_t)node * 64 + lane];        // self message
        int done = 0;
        while (done < dg) {
            int chunk = dg - done; if (chunk > 64) chunk = 64;
            int cv = (lane < chunk) ? col[rp + done + lane] : 0;
            for (int j = 0; j < chunk; ++j) {
                int s = __shfl(cv, j, 64);
                float2 v = hs2[(size_t)s * 64 + lane];
                acc.x += v.x; acc.y += v.y;
            }
            done += chunk;
        }
        float o0 = acc.x * dn + bias[lane * 2];
        float o1 = acc.y * dn + bias[lane * 2 + 1];
        if (RELU) { o0 = fmaxf(o0, 0.f); o1 = fmaxf(o1, 0.f); }
        ((float2*)out)[(size_t)node * 64 + lane] = make_float2(o0, o1);
    } else {
        float acc = hs[(size_t)node * 64 + lane];          // self message
        int done = 0;
        while (done < dg) {
            int chunk = dg - done; if (chunk > 64) chunk = 64;
            int cv = (lane < chunk) ? col[rp + done + lane] : 0;
            for (int j = 0; j < chunk; ++j) {
                int s = __shfl(cv, j, 64);
                acc += hs[(size_t)s * 64 + lane];
            }
            done += chunk;
        }
        float o = acc * dn + bias[lane];
        if (RELU) o = fmaxf(o, 0.f);
        out[(size_t)node * 64 + lane] = o;
    }
}

// ---------------------------------------------------------------------------
// logits[e] = dot(z[s], z[d]) over 64 features; one wave per edge.
// ---------------------------------------------------------------------------
__global__ __launch_bounds__(256) void logits_kernel(
        const int* __restrict__ pos, const int* __restrict__ neg,
        const float* __restrict__ z, float* __restrict__ out) {
    const int t    = threadIdx.x;
    const int lane = t & 63;
    const int e    = blockIdx.x * 4 + (t >> 6);
    if (e >= 2 * E_PAIR) return;
    int s, d;
    if (e < E_PAIR) { s = pos[e];          d = pos[E_PAIR + e]; }
    else            { s = neg[e - E_PAIR]; d = neg[e];          }
    float v = z[(size_t)s * C_OUT + lane] * z[(size_t)d * C_OUT + lane];
#pragma unroll
    for (int off = 32; off > 0; off >>= 1) v += __shfl_down(v, off, 64);
    if (lane == 0) out[e] = v;
}

// ---------------------------------------------------------------------------
extern "C" void kernel_launch(void* const* d_in, const int* in_sizes, int n_in,
                              void* d_out, int out_size, void* d_ws, size_t ws_size,
                              hipStream_t stream) {
    const float* x   = (const float*)d_in[0];
    const int*   ei  = (const int*)d_in[1];   // [2, E] : row0=src, row1=dst
    const int*   pos = (const int*)d_in[2];   // [2, E_PAIR]
    const int*   neg = (const int*)d_in[3];   // [2, E_PAIR]
    const float* W1  = (const float*)d_in[4];
    const float* b1  = (const float*)d_in[5];
    const float* W2  = (const float*)d_in[6];
    const float* b2  = (const float*)d_in[7];
    float* out = (float*)d_out;

    const int* src = ei;
    const int* dst = ei + E_EDGES;

    // Workspace layout (256B-aligned offsets):
    //   degc:    int[50000] + counter at degc[50000]     @ 0        (200704 B)
    //   row_ptr: int[50000]                              @ 200704
    //   cursor:  int[50000]                              @ 401408
    //   dinv:    float[50000]                            @ 602112
    //   col:     int[800000]                             @ 802816   (3200000 B)
    //   bufA:    float[50000*128]                        @ 4002816  (25.6 MB)
    //   bufB:    float[50000*128]                        @ 29602816 (25.6 MB)
    // total ~55.2 MB
    char* ws = (char*)d_ws;
    int*   degc    = (int*)ws;
    int*   counter = degc + N_NODES;
    int*   row_ptr = (int*)(ws + 200704);
    int*   cursor  = (int*)(ws + 401408);
    float* dinv    = (float*)(ws + 602112);
    int*   col     = (int*)(ws + 802816);
    float* bufA    = (float*)(ws + 4002816);
    float* bufB    = (float*)(ws + 29602816);
    float* z0s  = bufA;                       // 50000*64
    float* zbuf = bufA + N_NODES * C_OUT;     // 50000*64

    // 1. CSR build (by destination) + dinv
    hipMemsetAsync(degc, 0, (N_NODES + 1) * sizeof(int), stream);
    count_kernel<<<(E_EDGES + 255) / 256, 256, 0, stream>>>(dst, degc);
    alloc_kernel<<<(N_NODES + 1023) / 1024, 256, 0, stream>>>(degc, counter, row_ptr, cursor, dinv);
    fill_kernel<<<(E_EDGES + 255) / 256, 256, 0, stream>>>(src, dst, cursor, col);

    // 2. h0' = (x@W1) * dinv[row]  -> bufA
    gemm1_kernel<<<N_NODES / 8, 256, 0, stream>>>(x, W1, dinv, bufA);

    // 3. h = relu((gather + self)*dinv + b1) -> bufB
    gather_kernel<C_HID, true><<<(N_NODES + 3) / 4, 256, 0, stream>>>(
        row_ptr, degc, col, bufA, dinv, b1, bufB);

    // 4. z0' = (h@W2) * dinv[row] -> z0s; z = gather -> zbuf
    gemm2_kernel<<<N_NODES / 16, 256, 0, stream>>>(bufB, W2, dinv, z0s);
    gather_kernel<C_OUT, false><<<(N_NODES + 3) / 4, 256, 0, stream>>>(
        row_ptr, degc, col, z0s, dinv, b2, zbuf);

    // 5. logits over 400000 query edges
    logits_kernel<<<(2 * E_PAIR + 3) / 4, 256, 0, stream>>>(pos, neg, zbuf, out);
}